// Round 12
// baseline (146.786 us; speedup 1.0000x reference)
//
#include <hip/hip_runtime.h>
#include <hip/hip_bf16.h>

// ---------------- problem constants ----------------
#define CHW   1048576        // 256*64*64
// ws layout (bytes)
#define XQ_BYTES 17842176u   // 16*66*66*256 (i8)
#define WQ_OFF   17842176u   // 9*256*256 i8 = 589824
#define GNP_OFF  18432000u   // double2[1024]
#define CMM_OFF  18448384u   // float2[4096]
#define MR_OFF   18481152u   // float2[16]
#define SC_OFF   18481280u   // float[4]
#define WP_OFF   18481296u   // double[36]
#define DL_OFF   18481584u   // float delta
#define EVC_OFF  18481588u   // int event count
#define EVL_OFF  18481592u   // int[1024] event list

typedef __attribute__((ext_vector_type(4)))  int i32x4;
typedef __attribute__((ext_vector_type(16))) int i32x16;

__device__ __forceinline__ void gload16(const void* g, void* l) {
    __builtin_amdgcn_global_load_lds(
        (const __attribute__((address_space(1))) unsigned int*)(unsigned long long)(g),
        (__attribute__((address_space(3))) unsigned int*)(unsigned int)(unsigned long long)(l),
        16, 0, 0);
}

// ---------- K1: fused per-sample sum/sumsq + per-(n,c) min/max (grid 1024, block 256) ----------
__global__ void k_pass1(const float* __restrict__ x, double2* __restrict__ part,
                        float2* __restrict__ cmm) {
    int bid = blockIdx.x;
    int n = bid >> 6, c4 = bid & 63;
    int t = threadIdx.x, ch = t >> 6, lane = t & 63;
    int c = c4 * 4 + ch;
    const float4* p = (const float4*)(x + (size_t)n * CHW + (size_t)c * 4096);
    double s = 0.0, ss = 0.0;
    float mn = 1e30f, mx = -1e30f;
#pragma unroll
    for (int k = 0; k < 16; ++k) {
        float4 v = p[k * 64 + lane];
        mn = fminf(mn, fminf(fminf(v.x, v.y), fminf(v.z, v.w)));
        mx = fmaxf(mx, fmaxf(fmaxf(v.x, v.y), fmaxf(v.z, v.w)));
        double dx = v.x, dy = v.y, dz = v.z, dw = v.w;
        s  += dx + dy + dz + dw;
        ss += dx * dx + dy * dy + dz * dz + dw * dw;
    }
    for (int o = 32; o; o >>= 1) {
        s += __shfl_down(s, o); ss += __shfl_down(ss, o);
        mn = fminf(mn, __shfl_down(mn, o)); mx = fmaxf(mx, __shfl_down(mx, o));
    }
    __shared__ double sh0[4], sh1[4];
    if (lane == 0) {
        cmm[n * 256 + c] = make_float2(mn, mx);
        sh0[ch] = s; sh1[ch] = ss;
    }
    __syncthreads();
    if (t == 0)
        part[bid] = make_double2(sh0[0] + sh0[1] + sh0[2] + sh0[3],
                                 sh1[0] + sh1[1] + sh1[2] + sh1[3]);
}

// ---------- K2: partial sum |W| (grid 36, block 256) ----------
__global__ void k_wsum(const float* __restrict__ w, double* __restrict__ wp) {
    int blk = blockIdx.x, t = threadIdx.x;
    const float4* p = (const float4*)(w + (size_t)blk * 16384);
    double s = 0.0;
#pragma unroll
    for (int j = 0; j < 16; ++j) {
        float4 v = p[j * 256 + t];
        s += fabs((double)v.x) + fabs((double)v.y) + fabs((double)v.z) + fabs((double)v.w);
    }
    for (int o = 32; o; o >>= 1) s += __shfl_down(s, o);
    __shared__ double sh[4];
    if ((t & 63) == 0) sh[t >> 6] = s;
    __syncthreads();
    if (t == 0) wp[blk] = sh[0] + sh[1] + sh[2] + sh[3];
}

// ---------- K3: all scalar reductions in one block ----------
__global__ void k_scalars(const double2* __restrict__ part, const float2* __restrict__ cmm,
                          const float* __restrict__ lnw, const float* __restrict__ lnb,
                          const double* __restrict__ wp,
                          float2* __restrict__ mr, float* __restrict__ sc,
                          float* __restrict__ dl, int* __restrict__ evcnt) {
    __shared__ float shm[16], shr[16];
    int t = threadIdx.x;                 // 256
    {   // mean / rstd: t = n*16 + i
        int n = t >> 4, i = t & 15;
        double s = 0.0, ss = 0.0;
#pragma unroll
        for (int k = 0; k < 4; ++k) {
            double2 v = part[n * 64 + i * 4 + k];
            s += v.x; ss += v.y;
        }
        for (int o = 8; o; o >>= 1) { s += __shfl_down(s, o); ss += __shfl_down(ss, o); }
        if (i == 0) {
            double mean = s * (1.0 / 1048576.0);
            double var  = ss * (1.0 / 1048576.0) - mean * mean;
            shm[n] = (float)mean; shr[n] = (float)(1.0 / sqrt(var + 1e-5));
        }
    }
    __syncthreads();
    if (t < 16) mr[t] = make_float2(shm[t], shr[t]);
    if (t == 0) evcnt[0] = 0;
    // gamma from per-channel min/max (affine endpoints)
    float m = 0.0f;
#pragma unroll
    for (int k = 0; k < 16; ++k) {
        int idx = t + k * 256;
        int n = idx >> 8, c = idx & 255;
        float2 v = cmm[idx];
        float scale = lnw[c] * shr[n];
        float shift = lnb[c] - shm[n] * scale;
        m = fmaxf(m, fmaxf(fabsf(v.x * scale + shift), fabsf(v.y * scale + shift)));
    }
    for (int o = 32; o; o >>= 1) m = fmaxf(m, __shfl_down(m, o));
    __shared__ float shg[4];
    if ((t & 63) == 0) shg[t >> 6] = m;
    __syncthreads();
    if (t == 0) {
        float gamma = fmaxf(fmaxf(fmaxf(shg[0], shg[1]), fmaxf(shg[2], shg[3])), 1e-6f);
        sc[0] = gamma;
        sc[1] = 128.0f / gamma;
        sc[2] = (gamma / 128.0f) * 0.01f;
    }
    // delta
    if (t < 64) {
        double s = (t < 36) ? wp[t] : 0.0;
        for (int o = 32; o; o >>= 1) s += __shfl_down(s, o);
        if (t == 0) dl[0] = (float)(0.7 * (s / 589824.0));
    }
}

// ---------- K4: ternary quantize W -> wq[tap][co][ci] i8 sign (grid 256, block 256) ----------
__global__ void k_wquant(const float* __restrict__ w, const float* __restrict__ dl,
                         signed char* __restrict__ wq) {
    __shared__ float sw[2304];
    int co = blockIdx.x, t = threadIdx.x;
    const float* wr = w + (size_t)co * 2304;
#pragma unroll
    for (int j = 0; j < 9; ++j) sw[j * 256 + t] = wr[j * 256 + t];
    __syncthreads();
    float d = dl[0];
#pragma unroll
    for (int tap = 0; tap < 9; ++tap) {
        float v = sw[t * 9 + tap];
        int s = (v > d) ? 1 : ((v < -d) ? -1 : 0);
        wq[tap * 65536 + co * 256 + t] = (signed char)s;
    }
}

// ---------- K5: zero only the halo of xq (grid 520, block 256) ----------
__global__ void k_halo(unsigned char* __restrict__ xq) {
    int idx = blockIdx.x * 8 + (threadIdx.x >> 5);   // 0..4159
    int n = idx / 260, p = idx - n * 260;
    int hh, ww;
    if (p < 66)       { hh = 0;        ww = p; }
    else if (p < 132) { hh = 65;       ww = p - 66; }
    else if (p < 196) { hh = p - 131;  ww = 0; }
    else              { hh = p - 195;  ww = 65; }
    *(uint2*)(xq + ((size_t)(n * 66 + hh) * 66 + ww) * 256 + (threadIdx.x & 31) * 8) =
        make_uint2(0, 0);
}

// ---------- K6: GN + quantize + NCHW -> padded NHWC i8 (grid 1024, block 256) ----------
__global__ void k_quantx(const float* __restrict__ x, const float2* __restrict__ mr,
                         const float* __restrict__ sc, const float* __restrict__ lnw,
                         const float* __restrict__ lnb, unsigned char* __restrict__ xq,
                         int* __restrict__ evcnt, int* __restrict__ evlist) {
    int bid = blockIdx.x;
    int n = bid >> 6, hg = (bid >> 2) & 15, cg = bid & 3;
    int t = threadIdx.x;
    int w = t & 63, h = hg * 4 + (t >> 6);
    float2 m = mr[n];
    float s128 = sc[1];
    uint u[16];
    const float* xp = x + (((size_t)n * 256 + cg * 64) * 64 + h) * 64 + w;
#pragma unroll
    for (int ci = 0; ci < 64; ++ci) {
        int c = cg * 64 + ci;
        float g = lnw[c] * m.y;
        float be = lnb[c];
        float v = xp[(size_t)ci * 4096];
        float xs = ((v - m.x) * g + be) * s128;
        xs = fminf(fmaxf(xs, -(128.0f - 1e-6f)), 128.0f - 1e-6f);
        int q = (int)rintf(xs);
        if (q == 128) {                         // i8 overflow: record, clamp
            int idx = atomicAdd(evcnt, 1);
            if (idx < 1024) evlist[idx] = (n << 20) | (h << 14) | (w << 8) | c;
            q = 127;
        }
        uint b = (uint)(q & 255);
        if ((ci & 3) == 0) u[ci >> 2] = b; else u[ci >> 2] |= b << ((ci & 3) * 8);
    }
    unsigned char* op = xq + ((size_t)(n * 66 + h + 1) * 66 + (w + 1)) * 256 + cg * 64;
    uint4* o4 = (uint4*)op;
#pragma unroll
    for (int s2 = 0; s2 < 4; ++s2)
        o4[s2] = make_uint4(u[s2 * 4], u[s2 * 4 + 1], u[s2 * 4 + 2], u[s2 * 4 + 3]);
}

// ---------- K8: saturation fixup (grid 64, block 256) ----------
__global__ void k_fix(const signed char* __restrict__ wq, const int* __restrict__ evcnt,
                      const int* __restrict__ evlist, const float* __restrict__ sc,
                      float* __restrict__ out) {
    int cnt = *evcnt; if (cnt > 1024) cnt = 1024;
    float qs = sc[2];
    int co = threadIdx.x;
    for (int e = blockIdx.x; e < cnt; e += gridDim.x) {
        int pk = evlist[e];
        int n = pk >> 20, h = (pk >> 14) & 63, w = (pk >> 8) & 63, ci = pk & 255;
#pragma unroll
        for (int ty = 0; ty < 3; ++ty)
#pragma unroll
            for (int tx = 0; tx < 3; ++tx) {
                int i = h + 1 - ty, j = w + 1 - tx;
                if (i < 0 || i > 63 || j < 0 || j > 63) continue;
                int sgn = wq[(ty * 3 + tx) * 65536 + co * 256 + ci];
                if (sgn)
                    atomicAdd(out + (((size_t)n * 256 + co) * 64 + i) * 64 + j,
                              qs * (float)sgn);
            }
    }
}

// ---------- K7: conv as implicit GEMM, i8 MFMA 32x32x32, reg-prefetch pipeline ----------
// grid 256 (16 n x 16 h-quads, XCD-swizzled), 512 thr (8 waves 2m x 4n)
// tile BM=256 spatial x BN=256 co; 36 K-steps of 64 ci (9 taps x 4) = 36 phases.
// LDS: 5 step-buffers x 32KB = 160KB; phase s: vmcnt(4) -> barrier -> prefetch
// step s+1 frags (buf (s+1)%5) into the idle reg set + stage step s+3 ->
// 16 MFMA on the loaded set. ds_read latency hides under MFMA; lgkm wait is
// compiler-placed before the NEXT phase's MFMAs.
#define ABUFB 32768
#define LD16(off) (*(const i32x4*)&lds8[(off)])
#define MFMA_I8(A, B, C) __builtin_amdgcn_mfma_i32_32x32x32_i8(A, B, C, 0, 0, 0)

#define STAGE_A(AS) { \
    const int _so = (AS) * ABUFB + wv * 1024; \
    gload16(aSrc + stA,         lds8 + _so); \
    gload16(aSrc + stA + 33792, lds8 + _so + 8192); \
    if (aKc < 3) { aKc++; stA += 64; } \
    else { aKc = 0; if (aTx < 2) { aTx++; stA += 64; } else { aTx = 0; stA += 16192; } } }

#define STAGE_B(BS) { \
    const int _so = (BS) * ABUFB + 16384 + wv * 1024; \
    gload16(bSrc + stB,         lds8 + _so); \
    gload16(bSrc + stB + 32768, lds8 + _so + 8192); \
    if (bKc < 3) { bKc++; stB += 64; } else { bKc = 0; stB += 65344; } }

#define LOADF(S, RB) { \
    const int _ab = (RB) * ABUFB; const int _bb = _ab + 16384; \
    S##a00 = LD16(_ab + rdA);        S##a01 = LD16((_ab + rdA) ^ 32); \
    S##a10 = LD16(_ab + rdA + 2048); S##a11 = LD16((_ab + rdA + 2048) ^ 32); \
    S##a20 = LD16(_ab + rdA + 4096); S##a21 = LD16((_ab + rdA + 4096) ^ 32); \
    S##a30 = LD16(_ab + rdA + 6144); S##a31 = LD16((_ab + rdA + 6144) ^ 32); \
    S##b00 = LD16(_bb + rdB);        S##b01 = LD16((_bb + rdB) ^ 32); \
    S##b10 = LD16(_bb + rdB + 2048); S##b11 = LD16((_bb + rdB + 2048) ^ 32); }

#define MFMAS(S) \
    acc[0][0] = MFMA_I8(S##a00, S##b00, acc[0][0]); acc[0][1] = MFMA_I8(S##a00, S##b10, acc[0][1]); \
    acc[1][0] = MFMA_I8(S##a10, S##b00, acc[1][0]); acc[1][1] = MFMA_I8(S##a10, S##b10, acc[1][1]); \
    acc[2][0] = MFMA_I8(S##a20, S##b00, acc[2][0]); acc[2][1] = MFMA_I8(S##a20, S##b10, acc[2][1]); \
    acc[3][0] = MFMA_I8(S##a30, S##b00, acc[3][0]); acc[3][1] = MFMA_I8(S##a30, S##b10, acc[3][1]); \
    acc[0][0] = MFMA_I8(S##a01, S##b01, acc[0][0]); acc[0][1] = MFMA_I8(S##a01, S##b11, acc[0][1]); \
    acc[1][0] = MFMA_I8(S##a11, S##b01, acc[1][0]); acc[1][1] = MFMA_I8(S##a11, S##b11, acc[1][1]); \
    acc[2][0] = MFMA_I8(S##a21, S##b01, acc[2][0]); acc[2][1] = MFMA_I8(S##a21, S##b11, acc[2][1]); \
    acc[3][0] = MFMA_I8(S##a31, S##b01, acc[3][0]); acc[3][1] = MFMA_I8(S##a31, S##b11, acc[3][1]);

// phase: vmcnt -> barrier -> prefetch(L, buf RBN) + stage(SB) -> MFMA(C)
#define PHASEP(RBN, SB, DO, W, L, C) { \
    if ((W) == 4)      { asm volatile("s_waitcnt vmcnt(4)" ::: "memory"); } \
    else if ((W) == 0) { asm volatile("s_waitcnt vmcnt(0)" ::: "memory"); } \
    if ((W) >= 0) { __builtin_amdgcn_s_barrier(); __builtin_amdgcn_sched_barrier(0); } \
    if ((RBN) >= 0) LOADF(L, RBN) \
    if (DO) { STAGE_A(SB) STAGE_B(SB) } \
    __builtin_amdgcn_s_setprio(1); \
    MFMAS(C) \
    __builtin_amdgcn_s_setprio(0); \
}

__global__ __launch_bounds__(512, 2) void k_conv(const unsigned char* __restrict__ xq,
                                                 const signed char* __restrict__ wq,
                                                 const float* __restrict__ sc,
                                                 const float* __restrict__ bias,
                                                 float* __restrict__ out) {
    __shared__ __align__(128) unsigned char lds8[163840];   // 160 KB = 5 x 32KB
    int t = threadIdx.x, wv = t >> 6, l = t & 63;
    int wm = wv >> 2, wn = wv & 3;
    int l31 = l & 31, l5 = l >> 5;

    // XCD-bijective swizzle (256 % 8 == 0)
    int bid = ((int)blockIdx.x & 7) * 32 + ((int)blockIdx.x >> 3);
    int n = bid >> 4, h2 = (bid & 15) << 2;

    // ----- staging constants -----
    int s_src = (l & 7) ^ (l >> 3);          // logical slot this lane fetches
    int sb2   = (s_src >> 2) & 1;            // row parity within pair
    int skc   = s_src & 3;                   // 16B chunk within 64B ci block
    int RA    = wv * 16 + ((l >> 3) << 1) + sb2;      // A tile row (line 0)
    int hsub  = RA >> 6, wA = RA & 63;
    const unsigned char* aSrc = xq +
        ((size_t)(n * 66 + h2 + hsub) * 66 + wA) * 256 + skc * 16;
    int coB = ((wv * 8 + (l >> 3)) << 1) + sb2;       // B tile row (line 0)
    const unsigned char* bSrc = (const unsigned char*)wq + (size_t)coB * 256 + skc * 16;

    // ----- read constants -----
    int q3    = (l31 >> 1) & 7;
    int s0    = ((l31 & 1) << 2) | l5;       // ks=0 slot; ks=1 = ^2 -> addr ^32
    int phys0 = s0 ^ q3;
    int rdA = (wm * 64 + (l31 >> 1)) * 128 + phys0 * 16;   // + _m*2048
    int rdB = (wn * 32 + (l31 >> 1)) * 128 + phys0 * 16;   // + nf*2048

    i32x16 acc[4][2] = {};
    i32x4 Ea00, Ea01, Ea10, Ea11, Ea20, Ea21, Ea30, Ea31, Eb00, Eb01, Eb10, Eb11;
    i32x4 Oa00, Oa01, Oa10, Oa11, Oa20, Oa21, Oa30, Oa31, Ob00, Ob01, Ob10, Ob11;

    // ----- prologue: stage steps 0,1,2 -> bufs 0,1,2; load step-0 frags -> E -----
    int stA = 0, aKc = 0, aTx = 0;
    int stB = 0, bKc = 0;
    STAGE_A(0) STAGE_B(0)
    STAGE_A(1) STAGE_B(1)
    STAGE_A(2) STAGE_B(2)
    asm volatile("s_waitcnt vmcnt(8)" ::: "memory");   // step 0 resident
    __builtin_amdgcn_s_barrier();
    __builtin_amdgcn_sched_barrier(0);
    LOADF(E, 0)

    // ----- main loop: phases s=0..29 (3 x 10); phase s: prefetch s+1, stage s+3 -----
#pragma unroll 1
    for (int it = 0; it < 3; ++it) {
        PHASEP(1, 3, 1, 4, O, E)
        PHASEP(2, 4, 1, 4, E, O)
        PHASEP(3, 0, 1, 4, O, E)
        PHASEP(4, 1, 1, 4, E, O)
        PHASEP(0, 2, 1, 4, O, E)
        PHASEP(1, 3, 1, 4, E, O)
        PHASEP(2, 4, 1, 4, O, E)
        PHASEP(3, 0, 1, 4, E, O)
        PHASEP(4, 1, 1, 4, O, E)
        PHASEP(0, 2, 1, 4, E, O)
    }
    // ----- tail: phases 30..35 -----
    PHASEP(1, 3, 1, 4, O, E)     // s=30: stages 33
    PHASEP(2, 4, 1, 4, E, O)     // s=31: stages 34
    PHASEP(3, 0, 1, 4, O, E)     // s=32: stages 35 -> buf0
    PHASEP(4, 0, 0, 4, E, O)     // s=33
    PHASEP(0, 0, 0, 0, O, E)     // s=34: drain
    PHASEP(-1, 0, 0, -1, E, O)   // s=35

    // ----- epilogue: LDS-transpose for coalesced stores -----
    // acc[m][nf] reg r: h = h2 + wm*2 + (m>>1), w = (m&1)*32 + (r&3)+8*(r>>2)+4*l5,
    // co = wn*64 + nf*32 + l31.  LDS: [2 wm][256 co][16 w-slots] float4, slot^(co&7).
    float qs = sc[2];
    float bv0 = bias[wn * 64 + l31];
    float bv1 = bias[wn * 64 + 32 + l31];
    __builtin_amdgcn_s_barrier();            // all loop LDS reads done before overwrite
    float4* lf = (float4*)lds8;
#pragma unroll
    for (int rh = 0; rh < 2; ++rh) {         // h sub-row: m>>1
#pragma unroll
        for (int mh = 0; mh < 2; ++mh) {     // w half: m&1
            int m = rh * 2 + mh;
#pragma unroll
            for (int nf = 0; nf < 2; ++nf) {
                int co = wn * 64 + nf * 32 + l31;
                float bv = nf ? bv1 : bv0;
                int rowb = (wm * 256 + co) * 16;
#pragma unroll
                for (int rg = 0; rg < 4; ++rg) {
                    int slot = mh * 8 + rg * 2 + l5;
                    float4 v;
                    v.x = (float)acc[m][nf][rg * 4 + 0] * qs + bv;
                    v.y = (float)acc[m][nf][rg * 4 + 1] * qs + bv;
                    v.z = (float)acc[m][nf][rg * 4 + 2] * qs + bv;
                    v.w = (float)acc[m][nf][rg * 4 + 3] * qs + bv;
                    lf[rowb + (slot ^ (co & 7))] = v;
                }
            }
        }
        __syncthreads();
        // readback + coalesced store: idx = t + i*512 -> {lw, co, hs}
#pragma unroll
        for (int i = 0; i < 16; ++i) {
            int idx = t + i * 512;
            int lw = idx & 15, co = (idx >> 4) & 255, hs = idx >> 12;
            float4 v = lf[(hs * 256 + co) * 16 + (lw ^ (co & 7))];
            int h = h2 + hs * 2 + rh;
            *(float4*)(out + ((size_t)(n * 256 + co) * 64 + h) * 64 + lw * 4) = v;
        }
        if (rh == 0) __syncthreads();
    }
}

extern "C" void kernel_launch(void* const* d_in, const int* in_sizes, int n_in,
                              void* d_out, int out_size, void* d_ws, size_t ws_size,
                              hipStream_t stream) {
    (void)in_sizes; (void)n_in; (void)out_size; (void)ws_size;
    const float* x    = (const float*)d_in[0];
    const float* wgt  = (const float*)d_in[1];
    const float* bias = (const float*)d_in[2];
    const float* lnw  = (const float*)d_in[3];
    const float* lnb  = (const float*)d_in[4];
    float* out = (float*)d_out;
    char* ws = (char*)d_ws;

    unsigned char* xq  = (unsigned char*)ws;
    signed char*   wq  = (signed char*)(ws + WQ_OFF);
    double2* gnp = (double2*)(ws + GNP_OFF);
    float2*  cmm = (float2*)(ws + CMM_OFF);
    float2*  mr  = (float2*)(ws + MR_OFF);
    float*   sc  = (float*)(ws + SC_OFF);
    double*  wp  = (double*)(ws + WP_OFF);
    float*   dl  = (float*)(ws + DL_OFF);
    int*     evc = (int*)(ws + EVC_OFF);
    int*     evl = (int*)(ws + EVL_OFF);

    k_pass1  <<<1024, 256, 0, stream>>>(x, gnp, cmm);
    k_wsum   <<<36,   256, 0, stream>>>(wgt, wp);
    k_scalars<<<1,    256, 0, stream>>>(gnp, cmm, lnw, lnb, wp, mr, sc, dl, evc);
    k_wquant <<<256,  256, 0, stream>>>(wgt, dl, wq);
    k_halo   <<<520,  256, 0, stream>>>(xq);
    k_quantx <<<1024, 256, 0, stream>>>(x, mr, sc, lnw, lnb, xq, evc, evl);
    k_conv   <<<256,  512, 0, stream>>>(xq, wq, sc, bias, out);
    k_fix    <<<64,   256, 0, stream>>>(wq, evc, evl, sc, out);
}

// Round 13
// 100.376 us; speedup vs baseline: 1.4624x; 1.4624x over previous
//
#include <hip/hip_runtime.h>
#include <hip/hip_bf16.h>

// ---------------- problem constants ----------------
#define CHW   1048576        // 256*64*64
// ws layout (bytes)
#define XQ_BYTES 17842176u   // 16*66*66*256 (i8)
#define WQ_OFF   17842176u   // 9*256*256 i8 = 589824
#define GNP_OFF  18432000u   // double2[1024]
#define CMM_OFF  18448384u   // float2[4096]
#define MR_OFF   18481152u   // float2[16]
#define SC_OFF   18481280u   // float[4]
#define WP_OFF   18481296u   // double[36]
#define DL_OFF   18481584u   // float delta
#define EVC_OFF  18481588u   // int event count
#define EVL_OFF  18481592u   // int[1024] event list

typedef __attribute__((ext_vector_type(4)))  int i32x4;
typedef __attribute__((ext_vector_type(16))) int i32x16;

__device__ __forceinline__ void gload16(const void* g, void* l) {
    __builtin_amdgcn_global_load_lds(
        (const __attribute__((address_space(1))) unsigned int*)(unsigned long long)(g),
        (__attribute__((address_space(3))) unsigned int*)(unsigned int)(unsigned long long)(l),
        16, 0, 0);
}

// ---------- K1: fused per-sample sum/sumsq + per-(n,c) min/max (grid 1024, block 256) ----------
__global__ void k_pass1(const float* __restrict__ x, double2* __restrict__ part,
                        float2* __restrict__ cmm) {
    int bid = blockIdx.x;
    int n = bid >> 6, c4 = bid & 63;
    int t = threadIdx.x, ch = t >> 6, lane = t & 63;
    int c = c4 * 4 + ch;
    const float4* p = (const float4*)(x + (size_t)n * CHW + (size_t)c * 4096);
    double s = 0.0, ss = 0.0;
    float mn = 1e30f, mx = -1e30f;
#pragma unroll
    for (int k = 0; k < 16; ++k) {
        float4 v = p[k * 64 + lane];
        mn = fminf(mn, fminf(fminf(v.x, v.y), fminf(v.z, v.w)));
        mx = fmaxf(mx, fmaxf(fmaxf(v.x, v.y), fmaxf(v.z, v.w)));
        double dx = v.x, dy = v.y, dz = v.z, dw = v.w;
        s  += dx + dy + dz + dw;
        ss += dx * dx + dy * dy + dz * dz + dw * dw;
    }
    for (int o = 32; o; o >>= 1) {
        s += __shfl_down(s, o); ss += __shfl_down(ss, o);
        mn = fminf(mn, __shfl_down(mn, o)); mx = fmaxf(mx, __shfl_down(mx, o));
    }
    __shared__ double sh0[4], sh1[4];
    if (lane == 0) {
        cmm[n * 256 + c] = make_float2(mn, mx);
        sh0[ch] = s; sh1[ch] = ss;
    }
    __syncthreads();
    if (t == 0)
        part[bid] = make_double2(sh0[0] + sh0[1] + sh0[2] + sh0[3],
                                 sh1[0] + sh1[1] + sh1[2] + sh1[3]);
}

// ---------- K2: partial sum |W| (grid 36, block 256) ----------
__global__ void k_wsum(const float* __restrict__ w, double* __restrict__ wp) {
    int blk = blockIdx.x, t = threadIdx.x;
    const float4* p = (const float4*)(w + (size_t)blk * 16384);
    double s = 0.0;
#pragma unroll
    for (int j = 0; j < 16; ++j) {
        float4 v = p[j * 256 + t];
        s += fabs((double)v.x) + fabs((double)v.y) + fabs((double)v.z) + fabs((double)v.w);
    }
    for (int o = 32; o; o >>= 1) s += __shfl_down(s, o);
    __shared__ double sh[4];
    if ((t & 63) == 0) sh[t >> 6] = s;
    __syncthreads();
    if (t == 0) wp[blk] = sh[0] + sh[1] + sh[2] + sh[3];
}

// ---------- K3: all scalar reductions in one block ----------
__global__ void k_scalars(const double2* __restrict__ part, const float2* __restrict__ cmm,
                          const float* __restrict__ lnw, const float* __restrict__ lnb,
                          const double* __restrict__ wp,
                          float2* __restrict__ mr, float* __restrict__ sc,
                          float* __restrict__ dl, int* __restrict__ evcnt) {
    __shared__ float shm[16], shr[16];
    int t = threadIdx.x;                 // 256
    {   // mean / rstd: t = n*16 + i
        int n = t >> 4, i = t & 15;
        double s = 0.0, ss = 0.0;
#pragma unroll
        for (int k = 0; k < 4; ++k) {
            double2 v = part[n * 64 + i * 4 + k];
            s += v.x; ss += v.y;
        }
        for (int o = 8; o; o >>= 1) { s += __shfl_down(s, o); ss += __shfl_down(ss, o); }
        if (i == 0) {
            double mean = s * (1.0 / 1048576.0);
            double var  = ss * (1.0 / 1048576.0) - mean * mean;
            shm[n] = (float)mean; shr[n] = (float)(1.0 / sqrt(var + 1e-5));
        }
    }
    __syncthreads();
    if (t < 16) mr[t] = make_float2(shm[t], shr[t]);
    if (t == 0) evcnt[0] = 0;
    // gamma from per-channel min/max (affine endpoints)
    float m = 0.0f;
#pragma unroll
    for (int k = 0; k < 16; ++k) {
        int idx = t + k * 256;
        int n = idx >> 8, c = idx & 255;
        float2 v = cmm[idx];
        float scale = lnw[c] * shr[n];
        float shift = lnb[c] - shm[n] * scale;
        m = fmaxf(m, fmaxf(fabsf(v.x * scale + shift), fabsf(v.y * scale + shift)));
    }
    for (int o = 32; o; o >>= 1) m = fmaxf(m, __shfl_down(m, o));
    __shared__ float shg[4];
    if ((t & 63) == 0) shg[t >> 6] = m;
    __syncthreads();
    if (t == 0) {
        float gamma = fmaxf(fmaxf(fmaxf(shg[0], shg[1]), fmaxf(shg[2], shg[3])), 1e-6f);
        sc[0] = gamma;
        sc[1] = 128.0f / gamma;
        sc[2] = (gamma / 128.0f) * 0.01f;
    }
    // delta
    if (t < 64) {
        double s = (t < 36) ? wp[t] : 0.0;
        for (int o = 32; o; o >>= 1) s += __shfl_down(s, o);
        if (t == 0) dl[0] = (float)(0.7 * (s / 589824.0));
    }
}

// ---------- K4: ternary quantize W -> wq[tap][co][ci] i8 sign (grid 256, block 256) ----------
__global__ void k_wquant(const float* __restrict__ w, const float* __restrict__ dl,
                         signed char* __restrict__ wq) {
    __shared__ float sw[2304];
    int co = blockIdx.x, t = threadIdx.x;
    const float* wr = w + (size_t)co * 2304;
#pragma unroll
    for (int j = 0; j < 9; ++j) sw[j * 256 + t] = wr[j * 256 + t];
    __syncthreads();
    float d = dl[0];
#pragma unroll
    for (int tap = 0; tap < 9; ++tap) {
        float v = sw[t * 9 + tap];
        int s = (v > d) ? 1 : ((v < -d) ? -1 : 0);
        wq[tap * 65536 + co * 256 + t] = (signed char)s;
    }
}

// ---------- K5: zero only the halo of xq (grid 520, block 256) ----------
__global__ void k_halo(unsigned char* __restrict__ xq) {
    int idx = blockIdx.x * 8 + (threadIdx.x >> 5);   // 0..4159
    int n = idx / 260, p = idx - n * 260;
    int hh, ww;
    if (p < 66)       { hh = 0;        ww = p; }
    else if (p < 132) { hh = 65;       ww = p - 66; }
    else if (p < 196) { hh = p - 131;  ww = 0; }
    else              { hh = p - 195;  ww = 65; }
    *(uint2*)(xq + ((size_t)(n * 66 + hh) * 66 + ww) * 256 + (threadIdx.x & 31) * 8) =
        make_uint2(0, 0);
}

// ---------- K6: GN + quantize + NCHW -> padded NHWC i8 (grid 1024, block 256) ----------
__global__ void k_quantx(const float* __restrict__ x, const float2* __restrict__ mr,
                         const float* __restrict__ sc, const float* __restrict__ lnw,
                         const float* __restrict__ lnb, unsigned char* __restrict__ xq,
                         int* __restrict__ evcnt, int* __restrict__ evlist) {
    int bid = blockIdx.x;
    int n = bid >> 6, hg = (bid >> 2) & 15, cg = bid & 3;
    int t = threadIdx.x;
    int w = t & 63, h = hg * 4 + (t >> 6);
    float2 m = mr[n];
    float s128 = sc[1];
    uint u[16];
    const float* xp = x + (((size_t)n * 256 + cg * 64) * 64 + h) * 64 + w;
#pragma unroll
    for (int ci = 0; ci < 64; ++ci) {
        int c = cg * 64 + ci;
        float g = lnw[c] * m.y;
        float be = lnb[c];
        float v = xp[(size_t)ci * 4096];
        float xs = ((v - m.x) * g + be) * s128;
        xs = fminf(fmaxf(xs, -(128.0f - 1e-6f)), 128.0f - 1e-6f);
        int q = (int)rintf(xs);
        if (q == 128) {                         // i8 overflow: record, clamp
            int idx = atomicAdd(evcnt, 1);
            if (idx < 1024) evlist[idx] = (n << 20) | (h << 14) | (w << 8) | c;
            q = 127;
        }
        uint b = (uint)(q & 255);
        if ((ci & 3) == 0) u[ci >> 2] = b; else u[ci >> 2] |= b << ((ci & 3) * 8);
    }
    unsigned char* op = xq + ((size_t)(n * 66 + h + 1) * 66 + (w + 1)) * 256 + cg * 64;
    uint4* o4 = (uint4*)op;
#pragma unroll
    for (int s2 = 0; s2 < 4; ++s2)
        o4[s2] = make_uint4(u[s2 * 4], u[s2 * 4 + 1], u[s2 * 4 + 2], u[s2 * 4 + 3]);
}

// ---------- K8: saturation fixup (grid 64, block 256) ----------
__global__ void k_fix(const signed char* __restrict__ wq, const int* __restrict__ evcnt,
                      const int* __restrict__ evlist, const float* __restrict__ sc,
                      float* __restrict__ out) {
    int cnt = *evcnt; if (cnt > 1024) cnt = 1024;
    float qs = sc[2];
    int co = threadIdx.x;
    for (int e = blockIdx.x; e < cnt; e += gridDim.x) {
        int pk = evlist[e];
        int n = pk >> 20, h = (pk >> 14) & 63, w = (pk >> 8) & 63, ci = pk & 255;
#pragma unroll
        for (int ty = 0; ty < 3; ++ty)
#pragma unroll
            for (int tx = 0; tx < 3; ++tx) {
                int i = h + 1 - ty, j = w + 1 - tx;
                if (i < 0 || i > 63 || j < 0 || j > 63) continue;
                int sgn = wq[(ty * 3 + tx) * 65536 + co * 256 + ci];
                if (sgn)
                    atomicAdd(out + (((size_t)n * 256 + co) * 64 + i) * 64 + j,
                              qs * (float)sgn);
            }
    }
}

// ---------- K7: conv as implicit GEMM, i8 MFMA 32x32x32, half-set frag pipeline ----------
// grid 256 (16 n x 16 h-quads, XCD-swizzled), 512 thr (8 waves 2m x 4n)
// tile BM=256 spatial x BN=256 co; 36 K-steps of 64 ci (9 taps x 4) = 36 phases.
// LDS: 5 step-buffers x 32KB = 160KB (1 block/CU).  Phase p (buf p%5):
//   issue second-half(p) 6 ds_reads + stage(p+3) 4 gloads
//   lgkmcnt(6) -> 8 MFMA on prefetched first-half(p)
//   issue first-half(p+1) 6 ds_reads (buf (p+1)%5; safe: vmcnt(4) retires stage 2 ahead)
//   lgkmcnt(6) -> 8 MFMA on second-half(p)
//   vmcnt(4); s_barrier          (ONE barrier per phase)
// All ds_read latency/drain rides under an 8-MFMA burst.
#define ABUFB 32768
#define LD16(off) (*(const i32x4*)&lds8[(off)])
#define MFMA_I8(A, B, C) __builtin_amdgcn_mfma_i32_32x32x32_i8(A, B, C, 0, 0, 0)

#define STAGE_A(AS) { \
    const int _so = (AS) * ABUFB + wv * 1024; \
    gload16(aSrc + stA,         lds8 + _so); \
    gload16(aSrc + stA + 33792, lds8 + _so + 8192); \
    if (aKc < 3) { aKc++; stA += 64; } \
    else { aKc = 0; if (aTx < 2) { aTx++; stA += 64; } else { aTx = 0; stA += 16192; } } }

#define STAGE_B(BS) { \
    const int _so = (BS) * ABUFB + 16384 + wv * 1024; \
    gload16(bSrc + stB,         lds8 + _so); \
    gload16(bSrc + stB + 32768, lds8 + _so + 8192); \
    if (bKc < 3) { bKc++; stB += 64; } else { bKc = 0; stB += 65344; } }

#define PHASE(RB, RBN, SB, DO, W, CUR, NXT) { \
    const int _ab = (RB) * ABUFB; \
    const int _bb = _ab + 16384; \
    i32x4 sb0 = LD16((_bb + rdB) ^ 32);        i32x4 sb1 = LD16((_bb + rdB + 2048) ^ 32); \
    i32x4 sa0 = LD16((_ab + rdA) ^ 32);        i32x4 sa1 = LD16((_ab + rdA + 2048) ^ 32); \
    i32x4 sa2 = LD16((_ab + rdA + 4096) ^ 32); i32x4 sa3 = LD16((_ab + rdA + 6144) ^ 32); \
    if (DO) { STAGE_A(SB) STAGE_B(SB) } \
    asm volatile("s_waitcnt lgkmcnt(6)" ::: "memory"); \
    __builtin_amdgcn_sched_barrier(0); \
    __builtin_amdgcn_s_setprio(1); \
    acc[0][0] = MFMA_I8(CUR##a0, CUR##b0, acc[0][0]); \
    acc[1][0] = MFMA_I8(CUR##a1, CUR##b0, acc[1][0]); \
    acc[2][0] = MFMA_I8(CUR##a2, CUR##b0, acc[2][0]); \
    acc[3][0] = MFMA_I8(CUR##a3, CUR##b0, acc[3][0]); \
    acc[0][1] = MFMA_I8(CUR##a0, CUR##b1, acc[0][1]); \
    acc[1][1] = MFMA_I8(CUR##a1, CUR##b1, acc[1][1]); \
    acc[2][1] = MFMA_I8(CUR##a2, CUR##b1, acc[2][1]); \
    acc[3][1] = MFMA_I8(CUR##a3, CUR##b1, acc[3][1]); \
    __builtin_amdgcn_s_setprio(0); \
    __builtin_amdgcn_sched_barrier(0); \
    if ((RBN) >= 0) { \
        const int _abn = (RBN) * ABUFB; const int _bbn = _abn + 16384; \
        NXT##b0 = LD16(_bbn + rdB);        NXT##b1 = LD16(_bbn + rdB + 2048); \
        NXT##a0 = LD16(_abn + rdA);        NXT##a1 = LD16(_abn + rdA + 2048); \
        NXT##a2 = LD16(_abn + rdA + 4096); NXT##a3 = LD16(_abn + rdA + 6144); \
        asm volatile("s_waitcnt lgkmcnt(6)" ::: "memory"); \
    } else { \
        asm volatile("s_waitcnt lgkmcnt(0)" ::: "memory"); \
    } \
    __builtin_amdgcn_sched_barrier(0); \
    __builtin_amdgcn_s_setprio(1); \
    acc[0][0] = MFMA_I8(sa0, sb0, acc[0][0]); \
    acc[1][0] = MFMA_I8(sa1, sb0, acc[1][0]); \
    acc[2][0] = MFMA_I8(sa2, sb0, acc[2][0]); \
    acc[3][0] = MFMA_I8(sa3, sb0, acc[3][0]); \
    acc[0][1] = MFMA_I8(sa0, sb1, acc[0][1]); \
    acc[1][1] = MFMA_I8(sa1, sb1, acc[1][1]); \
    acc[2][1] = MFMA_I8(sa2, sb1, acc[2][1]); \
    acc[3][1] = MFMA_I8(sa3, sb1, acc[3][1]); \
    __builtin_amdgcn_s_setprio(0); \
    if ((W) == 4)      { asm volatile("s_waitcnt vmcnt(4)" ::: "memory"); } \
    else if ((W) == 0) { asm volatile("s_waitcnt vmcnt(0)" ::: "memory"); } \
    if ((W) >= 0) { __builtin_amdgcn_s_barrier(); __builtin_amdgcn_sched_barrier(0); } \
}

__global__ __launch_bounds__(512) void k_conv(const unsigned char* __restrict__ xq,
                                              const signed char* __restrict__ wq,
                                              const float* __restrict__ sc,
                                              const float* __restrict__ bias,
                                              float* __restrict__ out) {
    __shared__ __align__(128) unsigned char lds8[163840];   // 160 KB = 5 x 32KB
    int t = threadIdx.x, wv = t >> 6, l = t & 63;
    int wm = wv >> 2, wn = wv & 3;
    int l31 = l & 31, l5 = l >> 5;

    // XCD-bijective swizzle (256 % 8 == 0)
    int bid = ((int)blockIdx.x & 7) * 32 + ((int)blockIdx.x >> 3);
    int n = bid >> 4, h2 = (bid & 15) << 2;

    // ----- staging constants -----
    int s_src = (l & 7) ^ (l >> 3);          // logical slot this lane fetches
    int sb2   = (s_src >> 2) & 1;            // row parity within pair
    int skc   = s_src & 3;                   // 16B chunk within 64B ci block
    int RA    = wv * 16 + ((l >> 3) << 1) + sb2;      // A tile row (line 0)
    int hsub  = RA >> 6, wA = RA & 63;
    const unsigned char* aSrc = xq +
        ((size_t)(n * 66 + h2 + hsub) * 66 + wA) * 256 + skc * 16;
    int coB = ((wv * 8 + (l >> 3)) << 1) + sb2;       // B tile row (line 0)
    const unsigned char* bSrc = (const unsigned char*)wq + (size_t)coB * 256 + skc * 16;

    // ----- read constants -----
    int q3    = (l31 >> 1) & 7;
    int s0    = ((l31 & 1) << 2) | l5;       // ks=0 slot; ks=1 = ^2 -> addr ^32
    int phys0 = s0 ^ q3;
    int rdA = (wm * 64 + (l31 >> 1)) * 128 + phys0 * 16;   // + _m*2048
    int rdB = (wn * 32 + (l31 >> 1)) * 128 + phys0 * 16;   // + nf*2048

    i32x16 acc[4][2] = {};
    i32x4 Ua0, Ua1, Ua2, Ua3, Ub0, Ub1;
    i32x4 Va0, Va1, Va2, Va3, Vb0, Vb1;

    // ----- prologue: stage steps 0,1,2 -> bufs 0,1,2 (12 gloads) -----
    int stA = 0, aKc = 0, aTx = 0;
    int stB = 0, bKc = 0;
    STAGE_A(0) STAGE_B(0)
    STAGE_A(1) STAGE_B(1)
    STAGE_A(2) STAGE_B(2)
    asm volatile("s_waitcnt vmcnt(4)" ::: "memory");   // bufs 0,1 resident; 2 in flight
    __builtin_amdgcn_s_barrier();
    __builtin_amdgcn_sched_barrier(0);
    // first-half of step 0 -> U
    Ub0 = LD16(16384 + rdB); Ub1 = LD16(16384 + rdB + 2048);
    Ua0 = LD16(rdA);         Ua1 = LD16(rdA + 2048);
    Ua2 = LD16(rdA + 4096);  Ua3 = LD16(rdA + 6144);

    // ----- main loop: phases 0..29 (3 x 10, parity-aligned) -----
#pragma unroll 1
    for (int it = 0; it < 3; ++it) {
        PHASE(0, 1, 3, 1, 4, U, V)
        PHASE(1, 2, 4, 1, 4, V, U)
        PHASE(2, 3, 0, 1, 4, U, V)
        PHASE(3, 4, 1, 1, 4, V, U)
        PHASE(4, 0, 2, 1, 4, U, V)
        PHASE(0, 1, 3, 1, 4, V, U)
        PHASE(1, 2, 4, 1, 4, U, V)
        PHASE(2, 3, 0, 1, 4, V, U)
        PHASE(3, 4, 1, 1, 4, U, V)
        PHASE(4, 0, 2, 1, 4, V, U)
    }
    // ----- tail: phases 30..35 -----
    PHASE(0, 1, 3, 1, 4, U, V)    // p=30: stages 33
    PHASE(1, 2, 4, 1, 4, V, U)    // p=31: stages 34
    PHASE(2, 3, 0, 1, 4, U, V)    // p=32: stages 35 -> buf0
    PHASE(3, 4, 0, 0, 0, V, U)    // p=33: drain (stage 32 lands)
    PHASE(4, 0, 0, 0, 0, U, V)    // p=34
    PHASE(0, -1, 0, 0, -1, V, U)  // p=35

    // ----- epilogue: LDS-transpose for coalesced stores -----
    // acc[m][nf] reg r: h = h2 + wm*2 + (m>>1), w = (m&1)*32 + (r&3)+8*(r>>2)+4*l5,
    // co = wn*64 + nf*32 + l31.  LDS: [2 wm][256 co][16 w-slots] float4, slot^(co&7).
    float qs = sc[2];
    float bv0 = bias[wn * 64 + l31];
    float bv1 = bias[wn * 64 + 32 + l31];
    __builtin_amdgcn_s_barrier();            // all loop LDS reads done before overwrite
    float4* lf = (float4*)lds8;
#pragma unroll
    for (int rh = 0; rh < 2; ++rh) {         // h sub-row: m>>1
#pragma unroll
        for (int mh = 0; mh < 2; ++mh) {     // w half: m&1
            int m = rh * 2 + mh;
#pragma unroll
            for (int nf = 0; nf < 2; ++nf) {
                int co = wn * 64 + nf * 32 + l31;
                float bv = nf ? bv1 : bv0;
                int rowb = (wm * 256 + co) * 16;
#pragma unroll
                for (int rg = 0; rg < 4; ++rg) {
                    int slot = mh * 8 + rg * 2 + l5;
                    float4 v;
                    v.x = (float)acc[m][nf][rg * 4 + 0] * qs + bv;
                    v.y = (float)acc[m][nf][rg * 4 + 1] * qs + bv;
                    v.z = (float)acc[m][nf][rg * 4 + 2] * qs + bv;
                    v.w = (float)acc[m][nf][rg * 4 + 3] * qs + bv;
                    lf[rowb + (slot ^ (co & 7))] = v;
                }
            }
        }
        __syncthreads();
        // readback + coalesced store: idx = t + i*512 -> {lw, co, hs}
#pragma unroll
        for (int i = 0; i < 16; ++i) {
            int idx = t + i * 512;
            int lw = idx & 15, co = (idx >> 4) & 255, hs = idx >> 12;
            float4 v = lf[(hs * 256 + co) * 16 + (lw ^ (co & 7))];
            int h = h2 + hs * 2 + rh;
            *(float4*)(out + ((size_t)(n * 256 + co) * 64 + h) * 64 + lw * 4) = v;
        }
        if (rh == 0) __syncthreads();
    }
}

extern "C" void kernel_launch(void* const* d_in, const int* in_sizes, int n_in,
                              void* d_out, int out_size, void* d_ws, size_t ws_size,
                              hipStream_t stream) {
    (void)in_sizes; (void)n_in; (void)out_size; (void)ws_size;
    const float* x    = (const float*)d_in[0];
    const float* wgt  = (const float*)d_in[1];
    const float* bias = (const float*)d_in[2];
    const float* lnw  = (const float*)d_in[3];
    const float* lnb  = (const float*)d_in[4];
    float* out = (float*)d_out;
    char* ws = (char*)d_ws;

    unsigned char* xq  = (unsigned char*)ws;
    signed char*   wq  = (signed char*)(ws + WQ_OFF);
    double2* gnp = (double2*)(ws + GNP_OFF);
    float2*  cmm = (float2*)(ws + CMM_OFF);
    float2*  mr  = (float2*)(ws + MR_OFF);
    float*   sc  = (float*)(ws + SC_OFF);
    double*  wp  = (double*)(ws + WP_OFF);
    float*   dl  = (float*)(ws + DL_OFF);
    int*     evc = (int*)(ws + EVC_OFF);
    int*     evl = (int*)(ws + EVL_OFF);

    k_pass1  <<<1024, 256, 0, stream>>>(x, gnp, cmm);
    k_wsum   <<<36,   256, 0, stream>>>(wgt, wp);
    k_scalars<<<1,    256, 0, stream>>>(gnp, cmm, lnw, lnb, wp, mr, sc, dl, evc);
    k_wquant <<<256,  256, 0, stream>>>(wgt, dl, wq);
    k_halo   <<<520,  256, 0, stream>>>(xq);
    k_quantx <<<1024, 256, 0, stream>>>(x, mr, sc, lnw, lnb, xq, evc, evl);
    k_conv   <<<256,  512, 0, stream>>>(xq, wq, sc, bias, out);
    k_fix    <<<64,   256, 0, stream>>>(wq, evc, evl, sc, out);
}